// Round 4
// baseline (1032.024 us; speedup 1.0000x reference)
//
#include <hip/hip_runtime.h>
#include <math.h>

typedef float2 cplx;
#define PI_F 3.14159265358979323846f
#define C8F 0.70710678118654752440f

__device__ __forceinline__ cplx cadd(cplx a, cplx b){ return make_float2(a.x+b.x, a.y+b.y); }
__device__ __forceinline__ cplx csub(cplx a, cplx b){ return make_float2(a.x-b.x, a.y-b.y); }
__device__ __forceinline__ cplx cmul(cplx a, cplx b){ return make_float2(a.x*b.x - a.y*b.y, a.x*b.y + a.y*b.x); }
__device__ __forceinline__ cplx cmulc(cplx a, cplx b){ return make_float2(a.x*b.x + a.y*b.y, a.y*b.x - a.x*b.y); }
__device__ __forceinline__ cplx cax(float s, cplx v){ return make_float2(s*v.x, s*v.y); }

template<bool INV>
__device__ __forceinline__ void dft8(cplx* v) {
    cplx t0 = cadd(v[0], v[4]), u0 = csub(v[0], v[4]);
    cplx t1 = cadd(v[1], v[5]), u1 = csub(v[1], v[5]);
    cplx t2 = cadd(v[2], v[6]), u2 = csub(v[2], v[6]);
    cplx t3 = cadd(v[3], v[7]), u3 = csub(v[3], v[7]);
    if (!INV) {
        u1 = make_float2(C8F*(u1.x + u1.y), C8F*(u1.y - u1.x));
        u2 = make_float2(u2.y, -u2.x);
        u3 = make_float2(C8F*(u3.y - u3.x), -C8F*(u3.x + u3.y));
    } else {
        u1 = make_float2(C8F*(u1.x - u1.y), C8F*(u1.x + u1.y));
        u2 = make_float2(-u2.y, u2.x);
        u3 = make_float2(-C8F*(u3.x + u3.y), C8F*(u3.x - u3.y));
    }
    cplx b0 = cadd(t0,t2), b1 = cadd(t1,t3), b2 = csub(t0,t2), b3 = csub(t1,t3);
    b3 = INV ? make_float2(-b3.y, b3.x) : make_float2(b3.y, -b3.x);
    v[0] = cadd(b0,b1); v[4] = csub(b0,b1); v[2] = cadd(b2,b3); v[6] = csub(b2,b3);
    cplx c0 = cadd(u0,u2), c1 = cadd(u1,u3), c2 = csub(u0,u2), c3 = csub(u1,u3);
    c3 = INV ? make_float2(-c3.y, c3.x) : make_float2(c3.y, -c3.x);
    v[1] = cadd(c0,c1); v[5] = csub(c0,c1); v[3] = cadd(c2,c3); v[7] = csub(c2,c3);
}

template<bool INV>
__device__ __forceinline__ void dft4(cplx* v) {
    cplx b0 = cadd(v[0], v[2]), b2 = csub(v[0], v[2]);
    cplx b1 = cadd(v[1], v[3]), b3 = csub(v[1], v[3]);
    b3 = INV ? make_float2(-b3.y, b3.x) : make_float2(b3.y, -b3.x);
    v[0] = cadd(b0,b1); v[2] = csub(b0,b1); v[1] = cadd(b2,b3); v[3] = csub(b2,b3);
}

// 16-point DFT, natural in/out.
template<bool INV>
__device__ __forceinline__ void dft16(cplx* v) {
    #pragma unroll
    for (int a = 0; a < 4; ++a) {
        cplx t[4] = { v[a], v[a+4], v[a+8], v[a+12] };
        dft4<INV>(t);
        v[a] = t[0]; v[a+4] = t[1]; v[a+8] = t[2]; v[a+12] = t[3];
    }
    const float C1 = 0.92387953251128674f, S1 = 0.38268343236508978f, R2 = 0.70710678118654752f;
    #define TWX(idx, CR, CI) v[idx] = cmul(v[idx], make_float2(CR, INV ? -(CI) : (CI)))
    TWX(1+4*1,  C1, -S1);
    TWX(1+4*2,  R2, -R2);
    TWX(1+4*3,  S1, -C1);
    TWX(2+4*1,  R2, -R2);
    TWX(2+4*2, 0.f, -1.f);
    TWX(2+4*3, -R2, -R2);
    TWX(3+4*1,  S1, -C1);
    TWX(3+4*2, -R2, -R2);
    TWX(3+4*3, -C1,  S1);
    #undef TWX
    cplx o[16];
    #pragma unroll
    for (int c = 0; c < 4; ++c) {
        cplx t[4] = { v[4*c+0], v[4*c+1], v[4*c+2], v[4*c+3] };
        dft4<INV>(t);
        o[c] = t[0]; o[c+4] = t[1]; o[c+8] = t[2]; o[c+12] = t[3];
    }
    #pragma unroll
    for (int i = 0; i < 16; ++i) v[i] = o[i];
}

// swizzled twiddle-table index (breaks bank collisions for strided products)
__device__ __forceinline__ int twp(int i){ return i + (i >> 4); }

// B: [512 t][256 h][128 w] cplx = 128 MiB (all of d_ws).
// Data lives at h<128; h>=128 of each plane is scratch (used by k345 for the
// even-half partial result; k3/k5 that used to write there are deleted).
__host__ __device__ __forceinline__ size_t idxB(int t, int h, int w) {
    return ((size_t)t * 256 + h) * 128 + w;
}

// K0a: compact row m of (mtx * gridz^4) into <=16 (val,col) pairs (banded).
__global__ __launch_bounds__(256) void k0_mtx(
        const float* __restrict__ mtx, const float* __restrict__ gridz,
        float* __restrict__ tv, int* __restrict__ tc) {
    int m = blockIdx.x, t = threadIdx.x;
    __shared__ float rv[256];
    float g = gridz[t]; float g2 = g * g;
    rv[t] = mtx[m * 256 + t] * (g2 * g2);
    __syncthreads();
    if (t == 0) {
        int cnt = 0;
        for (int k = 0; k < 256 && cnt < 16; ++k)
            if (rv[k] != 0.f) { tv[m*16 + cnt] = rv[k]; tc[m*16 + cnt] = k; ++cnt; }
        for (; cnt < 16; ++cnt) { tv[m*16 + cnt] = 0.f; tc[m*16 + cnt] = 0; }
    }
}

// K0b: compact row m of mtxi into <=8 (val,col) pairs; 1/2^25 ifft norm folded in.
__global__ __launch_bounds__(256) void k0_mtxi(
        const float* __restrict__ mtxi, float* __restrict__ tv, int* __restrict__ tc) {
    int m = blockIdx.x, t = threadIdx.x;
    const float S = 2.9802322387695312e-08f; // 1/2^25, exact
    __shared__ float rv[256];
    rv[t] = mtxi[m * 256 + t];
    __syncthreads();
    if (t == 0) {
        int cnt = 0;
        for (int k = 0; k < 256 && cnt < 8; ++k)
            if (rv[k] != 0.f) { tv[m*8 + cnt] = rv[k] * S; tc[m*8 + cnt] = k; ++cnt; }
        for (; cnt < 8; ++cnt) { tv[m*8 + cnt] = 0.f; tc[m*8 + cnt] = 0; }
    }
}

// K2': fused resample + forward 512-FFT along t. Reads feat, writes B[all t, h<128].
__global__ __launch_bounds__(512, 2) void k2_fftt(
        const float* __restrict__ feat, const float* __restrict__ tv,
        const int* __restrict__ tc, cplx* __restrict__ B) {
    const int h = blockIdx.x, w0 = blockIdx.y * 16;
    const int tid = threadIdx.x, ww = tid & 15, q = tid >> 4; // q in [0,32)
    __shared__ cplx buf[512 * 17];
    __shared__ cplx tw[512];
    { float s, c; sincosf(-(2.0f*PI_F/512.0f)*(float)tid, &s, &c); tw[tid] = make_float2(c, s); }
    cplx* f2 = buf;
    for (int idx = tid; idx < 4096; idx += 512) {
        int t = idx >> 4, w = idx & 15;
        size_t o = ((size_t)t * 128 + h) * 128 + w0 + w;
        f2[idx] = make_float2(feat[o], feat[o + 4194304]);
    }
    __syncthreads();
    cplx xa[2][8];
    for (int hi = 0; hi < 2; ++hi) {
        int u = q + 32*hi;
        #pragma unroll
        for (int p = 0; p < 8; ++p) {
            if (p < 4) {
                int m = u + 64*p;
                cplx acc = make_float2(0.f, 0.f);
                const float4* v4 = (const float4*)(tv + m*16);
                const int4*  c4 = (const int4*)(tc + m*16);
                #pragma unroll
                for (int jj = 0; jj < 4; ++jj) {
                    float4 vv = v4[jj]; int4 cc = c4[jj];
                    acc = cadd(acc, cax(vv.x, f2[cc.x*16 + ww]));
                    acc = cadd(acc, cax(vv.y, f2[cc.y*16 + ww]));
                    acc = cadd(acc, cax(vv.z, f2[cc.z*16 + ww]));
                    acc = cadd(acc, cax(vv.w, f2[cc.w*16 + ww]));
                }
                xa[hi][p] = acc;
            } else xa[hi][p] = make_float2(0.f, 0.f);
        }
    }
    dft8<false>(xa[0]); dft8<false>(xa[1]);
    __syncthreads();
    for (int hi = 0; hi < 2; ++hi) {
        int u = q + 32*hi;
        #pragma unroll
        for (int r = 1; r < 8; ++r) xa[hi][r] = cmul(xa[hi][r], tw[u * r]);
        #pragma unroll
        for (int r = 0; r < 8; ++r) buf[(64*r + u) * 17 + ww] = xa[hi][r];
    }
    __syncthreads();
    for (int hi = 0; hi < 2; ++hi) {
        int u = q + 32*hi, r1 = u >> 3, j = u & 7, base = 64*r1 + j;
        cplx y[8];
        #pragma unroll
        for (int p = 0; p < 8; ++p) y[p] = buf[(base + 8*p) * 17 + ww];
        dft8<false>(y);
        #pragma unroll
        for (int r2 = 1; r2 < 8; ++r2) y[r2] = cmul(y[r2], tw[8 * j * r2]);
        #pragma unroll
        for (int r2 = 0; r2 < 8; ++r2) buf[(base + 8*r2) * 17 + ww] = y[r2];
    }
    __syncthreads();
    for (int hi = 0; hi < 2; ++hi) {
        int m = q + 32*hi;
        cplx z[8];
        #pragma unroll
        for (int r = 0; r < 8; ++r) z[r] = buf[(8*m + r) * 17 + ww];
        dft8<false>(z);
        int kb = (m >> 3) + 8 * (m & 7);
        #pragma unroll
        for (int s2 = 0; s2 < 8; ++s2)
            B[idxB(kb + 64*s2, h, w0 + ww)] = z[s2];
    }
}

// Row engine (k4's verified core): one 256-pt w-line: zero-padded fwd FFT,
// psf multiply (Hermitian mirror via index reversal + conj when mir), inverse
// FFT, keep w<128 back in eb. ex = this team's 256-cplx exchange slot.
// Contains 2 block-wide syncs -> must be called unconditionally.
__device__ __forceinline__ void k4row(
        cplx* __restrict__ eb, const int kh, const bool mir, const int ktp,
        const int q, cplx* __restrict__ ex, const cplx* __restrict__ tw,
        const float* __restrict__ pr, const float* __restrict__ pim) {
    const int khp = mir ? ((256 - kh) & 255) : kh;
    const size_t lineP = ((size_t)ktp * 256 + khp) * 256;
    float prv[16], piv[16];
    #pragma unroll
    for (int k1 = 0; k1 < 16; ++k1) {
        int kw = q + 16*k1;
        int ip = mir ? ((256 - kw) & 255) : kw;
        prv[k1] = pr[lineP + ip];
        piv[k1] = mir ? -pim[lineP + ip] : pim[lineP + ip]; // fold conj into load
    }
    cplx x[16];
    #pragma unroll
    for (int n = 0; n < 8; ++n) x[n] = eb[n];
    #pragma unroll
    for (int n = 8; n < 16; ++n) x[n] = make_float2(0.f, 0.f);
    dft16<false>(x);
    #pragma unroll
    for (int k2 = 1; k2 < 16; ++k2) x[k2] = cmul(x[k2], tw[twp(q * k2)]);
    #pragma unroll
    for (int k2 = 0; k2 < 16; ++k2) ex[(q ^ k2) + 16*k2] = x[k2];
    __syncthreads();
    cplx z[16];
    #pragma unroll
    for (int n1 = 0; n1 < 16; ++n1) z[n1] = ex[(n1 ^ q) + 16*q];
    dft16<false>(z);                 // z[k1] = X[q + 16*k1]
    #pragma unroll
    for (int k1 = 0; k1 < 16; ++k1) z[k1] = cmul(z[k1], make_float2(prv[k1], piv[k1]));
    dft16<true>(z);
    #pragma unroll
    for (int n1 = 1; n1 < 16; ++n1) z[n1] = cmulc(z[n1], tw[twp(n1 * q)]);
    #pragma unroll
    for (int n1 = 0; n1 < 16; ++n1) ex[(n1 ^ q) + 16*q] = z[n1]; // own column
    __syncthreads();
    cplx y[16];
    #pragma unroll
    for (int k2 = 0; k2 < 16; ++k2) y[k2] = ex[(q ^ k2) + 16*k2];
    dft16<true>(y);                  // w = q + 16*n2, keep n2<8
    #pragma unroll
    for (int n = 0; n < 8; ++n) eb[n] = y[n];
}

// K345: per-plane fused fwd-h(256 via even/odd FFT128 halves) + w-engine+psf +
// inv-h. Replaces k3+k4+k5 (saves 448 MiB of HBM round trips).
//   X[2r]   = FFT128(x),  X[2r+1] = FFT128(x * W256^{-h})
//   x[h]    = IDFT128u(E')[h] + W256^{+h} * IDFT128u(O')[h]
// Even half: stash partial (C_e) in the dead h>=128 half of the plane; odd half
// reloads the input (L3-warm), adds C_e, writes final. Column FFT128 = dft16
// over a (h=8a+b) + W128^{-bc} + dft8 over b, all exchanges in-place in PL
// (row-uniform per wave -> contiguous, conflict-free). Row engine = k4row with
// per-team 256-cplx slots covering all of PL (E rows pre-read to regs first).
// psf: blocks paired (2i,2i+1)->(kt=i, 512-i) so the mirror plane's psf reads
// (reversed+conj, psf real) hit L2/L3 lines just fetched by the partner.
// No min-waves clause (round-1 spill lesson); batch calls are static (rule #20).
__global__ __launch_bounds__(1024) void k345(
        cplx* __restrict__ B, const float* __restrict__ pr, const float* __restrict__ pim) {
    const int bx = blockIdx.x;
    const int i = bx >> 1;
    const int kt = ((bx & 1) == 0) ? i : (i == 0 ? 256 : 512 - i);
    const bool mir = (kt > 256);
    const int ktp = mir ? 512 - kt : kt;
    const int tid = threadIdx.x;
    const int w = tid & 127, b = tid >> 7;     // column phases: h = 8a + b
    const int team = tid >> 4, q = tid & 15;   // row phases: 64 teams x 16 lanes
    __shared__ cplx PL[16384];                 // 128 KiB: plane-half workspace
    __shared__ cplx tw[272];                   // W256 table, twp-swizzled
    if (tid < 256) { float s, c; sincosf(-(2.0f*PI_F/256.0f)*(float)tid, &s, &c); tw[twp(tid)] = make_float2(c, s); }
    const size_t plane = (size_t)kt * 256 * 128;
    cplx* ex = PL + team * 256;
    __syncthreads();                           // tw ready

    #pragma unroll 1
    for (int odd = 0; odd < 2; ++odd) {
        // ---- load column slices from global (contiguous per a); odd twiddle ----
        cplx p[16];
        #pragma unroll
        for (int a = 0; a < 16; ++a)
            p[a] = B[plane + (size_t)(8*a + b)*128 + w];
        if (odd) {
            #pragma unroll
            for (int a = 0; a < 16; ++a) p[a] = cmul(p[a], tw[twp(8*a + b)]); // W256^{-h}
        }
        // ---- fwd col FFT128 stage 1: dft16 over a -> T[b][c]; * W128^{-bc} ----
        dft16<false>(p);
        #pragma unroll
        for (int c = 1; c < 16; ++c) p[c] = cmul(p[c], tw[twp(2*b*c)]);
        __syncthreads();                       // prior-pass PL readers done
        #pragma unroll
        for (int c = 0; c < 16; ++c) PL[(b + 8*c)*128 + w] = p[c];
        __syncthreads();
        // ---- stage 2: dft8 over b for c in {b, b+8} -> E[c+16d] ----
        cplx e[16];
        #pragma unroll
        for (int g = 0; g < 2; ++g) {
            int c = b + 8*g;
            cplx t8[8];
            #pragma unroll
            for (int b2 = 0; b2 < 8; ++b2) t8[b2] = PL[(b2 + 8*c)*128 + w];
            dft8<false>(t8);
            #pragma unroll
            for (int d = 0; d < 8; ++d) e[8*g + d] = t8[d];
        }
        __syncthreads();
        #pragma unroll
        for (int g = 0; g < 2; ++g) {
            int c = b + 8*g;
            #pragma unroll
            for (int d = 0; d < 8; ++d) PL[(c + 16*d)*128 + w] = e[8*g + d];
        }
        __syncthreads();
        // ---- row batches: rows team and team+64 (kh = 2r + odd) ----
        cplx e1[8], e2[8];
        #pragma unroll
        for (int n = 0; n < 8; ++n) e1[n] = PL[team*128 + q + 16*n];
        #pragma unroll
        for (int n = 0; n < 8; ++n) e2[n] = PL[(team + 64)*128 + q + 16*n];
        __syncthreads();                       // E safe in regs; PL becomes exchange
        k4row(e1, 2*team + odd, mir, ktp, q, ex, tw, pr, pim);
        __syncthreads();                       // batch-1 reads drained
        k4row(e2, 2*(team + 64) + odd, mir, ktp, q, ex, tw, pr, pim);
        __syncthreads();                       // batch-2 reads drained
        #pragma unroll
        for (int n = 0; n < 8; ++n) PL[team*128 + q + 16*n] = e1[n];
        #pragma unroll
        for (int n = 0; n < 8; ++n) PL[(team + 64)*128 + q + 16*n] = e2[n];
        __syncthreads();
        // ---- inverse col FFT128 stage 1: per c in {b,b+8}: dft8<true> over d ----
        cplx A[16];
        #pragma unroll
        for (int g = 0; g < 2; ++g) {
            int c = b + 8*g;
            cplx t8[8];
            #pragma unroll
            for (int d = 0; d < 8; ++d) t8[d] = PL[(c + 16*d)*128 + w];
            dft8<true>(t8);
            #pragma unroll
            for (int m = 0; m < 8; ++m) A[8*g + m] = t8[m]; // A[m][c]
        }
        __syncthreads();
        #pragma unroll
        for (int g = 0; g < 2; ++g) {
            int c = b + 8*g;
            #pragma unroll
            for (int m = 0; m < 8; ++m) PL[(8*c + m)*128 + w] = A[8*g + m];
        }
        __syncthreads();
        // ---- stage 2: v[c]=A[b][c]; * W128^{+bc}; dft16<true> -> x[8a+b] ----
        cplx v[16];
        #pragma unroll
        for (int c = 0; c < 16; ++c) v[c] = PL[(8*c + b)*128 + w];
        #pragma unroll
        for (int c = 1; c < 16; ++c) v[c] = cmulc(v[c], tw[twp(2*b*c)]);
        dft16<true>(v);
        if (!odd) {
            // stash even-half partial in the dead h>=128 half of this plane
            #pragma unroll
            for (int a = 0; a < 16; ++a)
                B[plane + (size_t)(128 + 8*a + b)*128 + w] = v[a];
        } else {
            #pragma unroll
            for (int a = 0; a < 16; ++a) {
                int h = 8*a + b;
                cplx xo = cmulc(v[a], tw[twp(h)]);            // * W256^{+h}
                cplx ce = B[plane + (size_t)(128 + h)*128 + w];
                B[plane + (size_t)h*128 + w] = cadd(ce, xo);
            }
        }
    }
}

// K6': inverse 512-FFT along t fused with mtxi output matvec. Writes d_out only.
__global__ __launch_bounds__(512, 2) void k6_ifftt(
        cplx* __restrict__ B, const float* __restrict__ tv, const int* __restrict__ tc,
        float* __restrict__ out) {
    const int h = blockIdx.x, w0 = blockIdx.y * 16;
    const int tid = threadIdx.x, ww = tid & 15, q = tid >> 4; // q in [0,32)
    __shared__ cplx buf[512 * 17];
    __shared__ cplx tw[512];
    { float s, c; sincosf(-(2.0f*PI_F/512.0f)*(float)tid, &s, &c); tw[tid] = make_float2(c, s); }
    cplx za[2][8];
    for (int hi = 0; hi < 2; ++hi) {
        int m = q + 32*hi, kb = (m >> 3) + 8 * (m & 7);
        #pragma unroll
        for (int s2 = 0; s2 < 8; ++s2) za[hi][s2] = B[idxB(kb + 64*s2, h, w0 + ww)];
    }
    for (int hi = 0; hi < 2; ++hi) {
        int m = q + 32*hi;
        dft8<true>(za[hi]);
        #pragma unroll
        for (int jj = 0; jj < 8; ++jj) buf[(8*m + jj) * 17 + ww] = za[hi][jj];
    }
    __syncthreads();
    for (int hi = 0; hi < 2; ++hi) {
        int u = q + 32*hi, r1 = u >> 3, j = u & 7, base = 64*r1 + j;
        cplx y[8];
        #pragma unroll
        for (int r2 = 0; r2 < 8; ++r2) y[r2] = buf[(base + 8*r2) * 17 + ww];
        #pragma unroll
        for (int r2 = 1; r2 < 8; ++r2) y[r2] = cmulc(y[r2], tw[8 * j * r2]);
        dft8<true>(y);
        #pragma unroll
        for (int p = 0; p < 8; ++p) buf[(base + 8*p) * 17 + ww] = y[p];
    }
    __syncthreads();
    cplx vol[2][4];
    for (int hi = 0; hi < 2; ++hi) {
        int u = q + 32*hi;
        cplx xo[8];
        #pragma unroll
        for (int r = 0; r < 8; ++r) xo[r] = buf[(64*r + u) * 17 + ww];
        #pragma unroll
        for (int r = 1; r < 8; ++r) xo[r] = cmulc(xo[r], tw[u * r]);
        dft8<true>(xo);
        #pragma unroll
        for (int p = 0; p < 4; ++p) vol[hi][p] = xo[p];  // t = u + 64p < 256
    }
    __syncthreads();
    for (int hi = 0; hi < 2; ++hi) {
        int u = q + 32*hi;
        #pragma unroll
        for (int p = 0; p < 4; ++p) buf[(u + 64*p) * 16 + ww] = vol[hi][p];
    }
    __syncthreads();
    for (int hi = 0; hi < 2; ++hi) {
        int u = q + 32*hi;
        #pragma unroll
        for (int p = 0; p < 4; ++p) {
            int m = u + 64*p;
            cplx acc = make_float2(0.f, 0.f);
            const float4* v4 = (const float4*)(tv + m*8);
            const int4*  c4 = (const int4*)(tc + m*8);
            #pragma unroll
            for (int jj = 0; jj < 2; ++jj) {
                float4 vv = v4[jj]; int4 cc = c4[jj];
                acc = cadd(acc, cax(vv.x, buf[cc.x*16 + ww]));
                acc = cadd(acc, cax(vv.y, buf[cc.y*16 + ww]));
                acc = cadd(acc, cax(vv.z, buf[cc.z*16 + ww]));
                acc = cadd(acc, cax(vv.w, buf[cc.w*16 + ww]));
            }
            out[((size_t)m * 128 + h) * 128 + w0 + ww] = acc.x;
            out[(((size_t)256 + m) * 128 + h) * 128 + w0 + ww] = acc.y;
        }
    }
}

extern "C" void kernel_launch(void* const* d_in, const int* in_sizes, int n_in,
                              void* d_out, int out_size, void* d_ws, size_t ws_size,
                              hipStream_t stream) {
    const float* feat  = (const float*)d_in[0];
    const float* gridz = (const float*)d_in[1];
    const float* mtx   = (const float*)d_in[2];
    const float* mtxi  = (const float*)d_in[3];
    const float* pr    = (const float*)d_in[4];
    const float* pim   = (const float*)d_in[5];
    cplx* B = (cplx*)d_ws; // 512*256*128*8 = 128 MiB
    float* out = (float*)d_out;

    // mtx table in plane-257 scratch (k2 consumes it before k345 overwrites)
    float* T1v = (float*)(B + idxB(257, 128, 0));
    int*   T1c = (int*)(T1v + 4096);
    // mtxi table in plane-0 scratch (built after k345; consumed by k6')
    float* T2v = (float*)(B + idxB(0, 128, 0));
    int*   T2c = (int*)(T2v + 2048);

    k0_mtx <<<256, 256, 0, stream>>>(mtx, gridz, T1v, T1c);
    k2_fftt<<<dim3(128, 8), 512, 0, stream>>>(feat, T1v, T1c, B);
    k345   <<<512, 1024, 0, stream>>>(B, pr, pim);
    k0_mtxi<<<256, 256, 0, stream>>>(mtxi, T2v, T2c);
    k6_ifftt<<<dim3(128, 8), 512, 0, stream>>>(B, T2v, T2c, out);
}